// Round 5
// baseline (429.954 us; speedup 1.0000x reference)
//
#include <hip/hip_runtime.h>

typedef _Float16 f16x8 __attribute__((ext_vector_type(8)));
typedef float    f32x4 __attribute__((ext_vector_type(4)));

#define NSTEP 512
#define CHUNK 4
#define NCHUNK (NSTEP / CHUNK)
#define LOG2E     1.4426950408889634f
#define TWOLOG2E  2.8853900817779268f

__device__ __forceinline__ float exp2_(float v) { return __builtin_amdgcn_exp2f(v); }

// Exp2-domain 7-trans LSTM activation. Gates arrive PRE-SCALED from the MFMA:
// gi,gf,go = -log2(e)*(preact), gg = +2log2(e)*(preact).
__device__ __forceinline__ float lstm_act_(float gi, float gf, float gg, float go, float& c) {
    float eg = exp2_(gg);
    float ei = exp2_(gi);
    float ef = exp2_(gf);
    float eo = exp2_(go);
    float X  = (eg + 1.0f) * (1.0f + ei);
    float Y  = 1.0f + ef;
    float r  = __builtin_amdgcn_rcpf(X * Y);
    c = fmaf(r * X, c, (eg - 1.0f) * (r * Y));
    float ec = exp2_(fminf(c * TWOLOG2E, 30.0f));
    float r2 = __builtin_amdgcn_rcpf((ec + 1.0f) * (1.0f + eo));
    return (ec - 1.0f) * r2;
}
__device__ __forceinline__ float sig_(float v) {
    return __builtin_amdgcn_rcpf(1.0f + exp2_(-v * LOG2E));
}
__device__ __forceinline__ float tanh_(float v) {
    return 1.0f - 2.0f * __builtin_amdgcn_rcpf(exp2_(v * TWOLOG2E) + 1.0f);
}

// lgkmcnt-only barrier: does NOT drain vmcnt, so global x-prefetch loads float
// across the whole chunk. asm "memory" fences pin LDS ops on both sides.
__device__ __forceinline__ void bar_() {
    asm volatile("s_waitcnt lgkmcnt(0)" ::: "memory");
    __builtin_amdgcn_s_barrier();
    asm volatile("" ::: "memory");
}

// R20: de-phased dual recurrences. R18's counters showed issue (585cy) and the
// serial chain (~550cy) are ADDITIVE -- lockstep waves never overlap them.
// Phase diversity requires an independent recurrence: 512 blocks x 8 batches,
// 2 blocks/CU (launch_bounds(256,2)), 2 waves/SIMD = one per block. Each
// block's ds_read/act-chain stall is filled by the partner block's trans/VALU
// issue. Panels stay 16 cols wide; batch cols 8..15 are zero-fed (bounded:
// ec clamp keeps dead cells finite; they are never stored). 4 waves x 4 tiles
// inside a block (R19's verified mapping). All R18 tricks retained.
__global__ __launch_bounds__(256, 2) void lstm_mfma16_kernel(
    const float* __restrict__ x,     const float* __restrict__ Wemb,
    const float* __restrict__ Wih1,  const float* __restrict__ Whh1,
    const float* __restrict__ b1,    const float* __restrict__ Wih2,
    const float* __restrict__ b2,    const float* __restrict__ Wout,
    const float* __restrict__ bout,  float* __restrict__ out)
{
    __shared__ __align__(16) _Float16 P[2][2][4][16][8];       // 4096 B  h-panel dbuf
    __shared__ __align__(16) _Float16 Pe[2][CHUNK][4][16][8];  // 8192 B  emb panel dbuf
    __shared__ __align__(16) float h2tmp[8 * 64];              // 2048 B
    __shared__ __align__(16) float h2s[256 * 8];               // 8192 B
    __shared__ float part[32 * 8 * 2];                         // 2048 B

    const int t   = threadIdx.x;
    const int l   = t & 63;
    const int w   = t >> 6;      // wave 0..3; owns tiles 4w..4w+3
    const int m   = l & 15;      // A-row / B col (batch col) / D col
    const int q   = l >> 4;      // quad
    const int b0  = blockIdx.x * 8;   // 8 live batches per block

    // ---- weight fragments for 4 tiles (exp2-domain scaled) -----------------
    f16x8 whh[4][2], whE[4];
    f32x4 bias4[4];
    #pragma unroll
    for (int tt = 0; tt < 4; ++tt) {
        const int tau = 4 * w + tt;
        const int g = m & 3;
        const float sc = (g == 2) ? TWOLOG2E : -LOG2E;
        const int n = g * 64 + 4 * tau + (m >> 2);
        #pragma unroll
        for (int c = 0; c < 2; ++c)
            #pragma unroll
            for (int jj = 0; jj < 8; ++jj)
                whh[tt][c][jj] = (_Float16)(Whh1[n * 64 + c * 32 + (q << 3) + jj] * sc);
        #pragma unroll
        for (int jj = 0; jj < 8; ++jj) {
            int k = (q << 3) + jj;
            whE[tt][jj] = (_Float16)((k < 20) ? Wih1[n * 20 + k] * sc : 0.0f);
        }
        #pragma unroll
        for (int r = 0; r < 4; ++r) {
            float scr = (r == 2) ? TWOLOG2E : -LOG2E;
            bias4[tt][r] = b1[r * 64 + 4 * tau + q] * scr;
        }
    }

    // lane's act cells: unit 16w + 4tt + q, batch col m
    _Float16* hw[4];
    #pragma unroll
    for (int tt = 0; tt < 4; ++tt) {
        const int myu = 16 * w + 4 * tt + q;
        hw[tt] = &P[0][myu >> 5][(myu >> 3) & 3][m][myu & 7];
    }
    const _Float16* rb = &P[0][0][q][m][0];   // B-fragment base (lane-linear)
    // parity stride = one P buffer = 1024 f16; Pe buffer stride = 2048 f16

    // ---- emb writer slots: v = t + 256k, k=0..2; valid iff v < 640 ---------
    // (8 batches x 20 dims x CHUNK steps = 640). pair = v/20 ->
    // (batch = pair&7, s = pair>>3), dim d = v%20
    const float* xp[3]; _Float16* pe[3];
    float we0[3], we1[3];
    bool val[3];
    float2 xv[3];
    #pragma unroll
    for (int k = 0; k < 3; ++k) {
        int v  = t + 256 * k;
        val[k] = (v < CHUNK * 160);
        int vv = val[k] ? v : 0;
        int d  = vv % 20, pr = vv / 20;
        int bb = pr & 7, s = pr >> 3;
        we0[k] = Wemb[2 * d];
        we1[k] = Wemb[2 * d + 1];
        pe[k]  = &Pe[0][s][d >> 3][bb][d & 7];
        xp[k]  = x + (size_t)(b0 + bb) * (2 * NSTEP) + 2 * s;
        xv[k]  = *(const float2*)xp[k];                    // chunk-0 data
    }

    // ---- zero P (h(-1)=0) and all of Pe (pads stay 0 forever) --------------
    #pragma unroll
    for (int k = 0; k < 8; ++k) ((_Float16*)P)[t + 256 * k] = (_Float16)0.0f;
    {
        _Float16* pz = (_Float16*)Pe;
        #pragma unroll
        for (int k = 0; k < 16; ++k) pz[t + 256 * k] = (_Float16)0.0f;
    }
    __syncthreads();
    // fill Pe[0] with chunk 0's panel, then prefetch chunk 1's x
    #pragma unroll
    for (int k = 0; k < 3; ++k)
        if (val[k])
            pe[k][0] = (_Float16)fmaxf(fmaf(xv[k].x, we0[k], xv[k].y * we1[k]), 0.0f);
    #pragma unroll
    for (int k = 0; k < 3; ++k) { xp[k] += 2 * CHUNK; xv[k] = *(const float2*)xp[k]; }
    __syncthreads();

    // ---- main recurrence: 128 chunks x 4 steps ------------------------------
    float cst[4] = {0.f, 0.f, 0.f, 0.f};
    for (int ch = 0; ch < NCHUNK; ++ch) {
        const int pb = ch & 1;                           // Pe read buffer
        const _Float16* peR = (const _Float16*)Pe + pb * 2048;

        // phase B: ax[tile][j] = Wih*e(t) + b, in registers (lane == consumer)
        f32x4 ax[4][CHUNK];
        #pragma unroll
        for (int j = 0; j < CHUNK; ++j) {
            f16x8 fe = *(const f16x8*)(peR + j * 512 + q * 128 + m * 8);
            #pragma unroll
            for (int tt = 0; tt < 4; ++tt)
                ax[tt][j] = __builtin_amdgcn_mfma_f32_16x16x32_f16(whE[tt], fe, bias4[tt], 0, 0, 0);
        }

        // phase C: 4 recurrence steps, parity static per unrolled slot
        #pragma unroll
        for (int j = 0; j < CHUNK; ++j) {
            const int pr = j & 1;
            f16x8 f0 = *(const f16x8*)(rb + pr * 1024);
            f16x8 f1 = *(const f16x8*)(rb + pr * 1024 + 512);
            f32x4 a[4];
            #pragma unroll
            for (int tt = 0; tt < 4; ++tt)
                a[tt] = __builtin_amdgcn_mfma_f32_16x16x32_f16(whh[tt][0], f0, ax[tt][j], 0, 0, 0);
            #pragma unroll
            for (int tt = 0; tt < 4; ++tt)
                a[tt] = __builtin_amdgcn_mfma_f32_16x16x32_f16(whh[tt][1], f1, a[tt], 0, 0, 0);
            #pragma unroll
            for (int tt = 0; tt < 4; ++tt) {
                float hv = lstm_act_(a[tt][0], a[tt][1], a[tt][2], a[tt][3], cst[tt]);
                hw[tt][(pr ^ 1) * 1024] = (_Float16)hv;
            }
            if (j == 0) {
                // write NEXT chunk's emb panel (buffer pb^1) from xv regs;
                // at ch==NCHUNK-1 this writes stale data to a dead buffer.
                #pragma unroll
                for (int k = 0; k < 3; ++k)
                    if (val[k])
                        pe[k][(pb ^ 1) * 2048] =
                            (_Float16)fmaxf(fmaf(xv[k].x, we0[k], xv[k].y * we1[k]), 0.0f);
                if (ch + 2 < NCHUNK) {
                    #pragma unroll
                    for (int k = 0; k < 3; ++k) { xp[k] += 2 * CHUNK; xv[k] = *(const float2*)xp[k]; }
                }
            }
            bar_();
        }
    }
    // final h(511) in P[0]

    // ---- epilogue: h64 to fp32 (512 live values, two per thread) -----------
    #pragma unroll
    for (int r = 0; r < 2; ++r) {
        int tt = t + 256 * r;
        int b = tt >> 6, k = tt & 63;          // b = 0..7 live batches
        h2tmp[tt] = (float)P[0][k >> 5][(k >> 3) & 3][b][k & 7];
    }
    __syncthreads();

    // ---- LSTM2 (single step, h=c=0 -> f-gate irrelevant) -------------------
    {
        const int u = t;                            // 256 units, 8 batches each
        float acci[8], accg[8], acco[8];
        float bi2 = b2[u], bg2 = b2[512 + u], bo2 = b2[768 + u];
        #pragma unroll
        for (int b = 0; b < 8; ++b) { acci[b] = bi2; accg[b] = bg2; acco[b] = bo2; }
        for (int k4 = 0; k4 < 64; k4 += 4) {
            float4 wi = *(const float4*)&Wih2[(size_t)u * 64 + k4];
            float4 wg = *(const float4*)&Wih2[(size_t)(512 + u) * 64 + k4];
            float4 wo = *(const float4*)&Wih2[(size_t)(768 + u) * 64 + k4];
            #pragma unroll
            for (int b = 0; b < 8; ++b) {
                float4 hb = *(const float4*)&h2tmp[b * 64 + k4];
                acci[b] += wi.x * hb.x + wi.y * hb.y + wi.z * hb.z + wi.w * hb.w;
                accg[b] += wg.x * hb.x + wg.y * hb.y + wg.z * hb.z + wg.w * hb.w;
                acco[b] += wo.x * hb.x + wo.y * hb.y + wo.z * hb.z + wo.w * hb.w;
            }
        }
        #pragma unroll
        for (int b = 0; b < 8; ++b) {
            float c2 = sig_(acci[b]) * tanh_(accg[b]);
            h2s[u * 8 + b] = sig_(acco[b]) * tanh_(c2);
        }
    }
    __syncthreads();

    // ---- output projection --------------------------------------------------
    {
        int b = t & 7, grp = t >> 3;             // 32 groups x 8 units
        float p0 = 0.f, p1 = 0.f;
        #pragma unroll
        for (int uu = grp * 8; uu < grp * 8 + 8; ++uu) {
            float hvv = h2s[uu * 8 + b];
            p0 += hvv * Wout[uu];
            p1 += hvv * Wout[256 + uu];
        }
        part[(grp * 8 + b) * 2 + 0] = p0;
        part[(grp * 8 + b) * 2 + 1] = p1;
    }
    __syncthreads();
    if (t < 16) {
        int b = t >> 1, o = t & 1;
        float s0 = bout[o];
        for (int grp = 0; grp < 32; ++grp) s0 += part[(grp * 8 + b) * 2 + o];
        out[(size_t)(b0 + b) * 2 + o] = s0;
    }
}

extern "C" void kernel_launch(void* const* d_in, const int* in_sizes, int n_in,
                              void* d_out, int out_size, void* d_ws, size_t ws_size,
                              hipStream_t stream) {
    const float* x    = (const float*)d_in[0];
    const float* Wemb = (const float*)d_in[1];
    const float* Wih1 = (const float*)d_in[2];
    const float* Whh1 = (const float*)d_in[3];
    const float* b1   = (const float*)d_in[4];
    const float* Wih2 = (const float*)d_in[5];
    // d_in[6] = Whh2: unused (h=c=0 at LSTM2's single step)
    const float* b2   = (const float*)d_in[7];
    const float* Wout = (const float*)d_in[8];
    const float* bout = (const float*)d_in[9];
    float* out = (float*)d_out;

    lstm_mfma16_kernel<<<512, 256, 0, stream>>>(
        x, Wemb, Wih1, Whh1, b1, Wih2, b2, Wout, bout, out);
}

// Round 6
// 354.066 us; speedup vs baseline: 1.2143x; 1.2143x over previous
//
#include <hip/hip_runtime.h>

typedef _Float16 f16x8 __attribute__((ext_vector_type(8)));
typedef float    f32x4 __attribute__((ext_vector_type(4)));

#define NSTEP 512
#define CHUNK 4
#define NCHUNK (NSTEP / CHUNK)
#define LOG2E     1.4426950408889634f
#define TWOLOG2E  2.8853900817779268f

__device__ __forceinline__ float exp2_(float v) { return __builtin_amdgcn_exp2f(v); }

// Exp2-domain 7-trans LSTM activation. Gates arrive PRE-SCALED from the MFMA:
// gi,gf,go = -log2(e)*(preact), gg = +2log2(e)*(preact).
__device__ __forceinline__ float lstm_act_(float gi, float gf, float gg, float go, float& c) {
    float eg = exp2_(gg);
    float ei = exp2_(gi);
    float ef = exp2_(gf);
    float eo = exp2_(go);
    float X  = (eg + 1.0f) * (1.0f + ei);
    float Y  = 1.0f + ef;
    float r  = __builtin_amdgcn_rcpf(X * Y);
    c = fmaf(r * X, c, (eg - 1.0f) * (r * Y));
    float ec = exp2_(fminf(c * TWOLOG2E, 30.0f));
    float r2 = __builtin_amdgcn_rcpf((ec + 1.0f) * (1.0f + eo));
    return (ec - 1.0f) * r2;
}
__device__ __forceinline__ float sig_(float v) {
    return __builtin_amdgcn_rcpf(1.0f + exp2_(-v * LOG2E));
}
__device__ __forceinline__ float tanh_(float v) {
    return 1.0f - 2.0f * __builtin_amdgcn_rcpf(exp2_(v * TWOLOG2E) + 1.0f);
}

// lgkmcnt-only barrier: does NOT drain vmcnt, so global x-prefetch loads float
// across the whole chunk. asm "memory" fences pin LDS ops on both sides.
__device__ __forceinline__ void bar_() {
    asm volatile("s_waitcnt lgkmcnt(0)" ::: "memory");
    __builtin_amdgcn_s_barrier();
    asm volatile("" ::: "memory");
}

// R21: staggered lo/hi half-barriers (revert to R18's 8-wave/16-batch base).
// Wave w owns tile w (units 4w..4w+3 = LO K-half) and tile 8+w (HI K-half).
// Step: act-A -> write-lo -> BAR -> [f0 read + mfma0(t+1) issued, latency
// hidden under act-B's trans burst] -> act-B -> write-hi -> BAR -> f1 read +
// mfma1 -> a(t+1). Only the f1->mfma1 tail stays exposed. ax precompute is
// pipelined one chunk ahead into two static register banks (CHUNK=4).
// Per-cell arithmetic identical to R18 (absmax-preserving).
__global__ __launch_bounds__(512, 2) void lstm_mfma16_kernel(
    const float* __restrict__ x,     const float* __restrict__ Wemb,
    const float* __restrict__ Wih1,  const float* __restrict__ Whh1,
    const float* __restrict__ b1,    const float* __restrict__ Wih2,
    const float* __restrict__ b2,    const float* __restrict__ Wout,
    const float* __restrict__ bout,  float* __restrict__ out)
{
    __shared__ __align__(16) _Float16 P[2][2][4][16][8];       // 4096 B  h-panel dbuf (kc0=lo,kc1=hi)
    __shared__ __align__(16) _Float16 Pe[2][CHUNK][4][16][8];  // 8192 B  emb panel dbuf
    __shared__ __align__(16) float h2tmp[16 * 64];             // 4096 B
    __shared__ __align__(16) float h2s[256 * 16];              // 16384 B
    __shared__ float part[32 * 16 * 2];                        // 4096 B

    const int t   = threadIdx.x;
    const int l   = t & 63;
    const int w   = t >> 6;      // wave 0..7; owns tiles w (lo), 8+w (hi)
    const int m   = l & 15;      // A-row / B col (batch) / D col
    const int q   = l >> 4;      // quad
    const int b0  = blockIdx.x * 16;

    // ---- weight fragments for both tiles (exp2-domain scaled) --------------
    f16x8 whhA[2], whhB[2], whEA, whEB;
    f32x4 biasA, biasB;
    {
        const int g = m & 3;
        const float sc = (g == 2) ? TWOLOG2E : -LOG2E;
        const int nA = g * 64 + 4 * w + (m >> 2);          // tile w
        const int nB = g * 64 + 4 * (8 + w) + (m >> 2);    // tile 8+w
        #pragma unroll
        for (int c = 0; c < 2; ++c)
            #pragma unroll
            for (int jj = 0; jj < 8; ++jj) {
                whhA[c][jj] = (_Float16)(Whh1[nA * 64 + c * 32 + (q << 3) + jj] * sc);
                whhB[c][jj] = (_Float16)(Whh1[nB * 64 + c * 32 + (q << 3) + jj] * sc);
            }
        #pragma unroll
        for (int jj = 0; jj < 8; ++jj) {
            int k = (q << 3) + jj;
            whEA[jj] = (_Float16)((k < 20) ? Wih1[nA * 20 + k] * sc : 0.0f);
            whEB[jj] = (_Float16)((k < 20) ? Wih1[nB * 20 + k] * sc : 0.0f);
        }
        #pragma unroll
        for (int r = 0; r < 4; ++r) {
            float scr = (r == 2) ? TWOLOG2E : -LOG2E;
            biasA[r] = b1[r * 64 + 4 * w + q] * scr;
            biasB[r] = b1[r * 64 + 4 * (8 + w) + q] * scr;
        }
    }

    // lane's act cells: unit 4w+q (lo, kc=0) and 32+4w+q (hi, kc=1), batch m
    const int us = 4 * w + q;                      // sub-index within half
    _Float16* hwA = &P[0][0][us >> 3][m][us & 7];  // lo slot
    _Float16* hwB = hwA + 512;                     // hi slot (kc stride = 512 f16)
    const _Float16* rb = &P[0][0][q][m][0];        // B-fragment base (lane-linear)
    // parity stride = one P buffer = 1024 f16; Pe buffer stride = 2048 f16

    // ---- emb writer slots: v = t + 512k, k=0..2; valid iff v < 1280 --------
    // (16 batches x 20 dims x CHUNK=4 steps). pair = v/20 ->
    // (batch = pair&15, s = pair>>4), dim d = v%20
    const float* xp[3]; _Float16* pe[3];
    float we0[3], we1[3];
    bool val[3];
    float2 xv[3];
    #pragma unroll
    for (int k = 0; k < 3; ++k) {
        int v  = t + 512 * k;
        val[k] = (v < CHUNK * 320);
        int vv = val[k] ? v : 0;
        int d  = vv % 20, pr = vv / 20;
        int bb = pr & 15, s = pr >> 4;
        we0[k] = Wemb[2 * d];
        we1[k] = Wemb[2 * d + 1];
        pe[k]  = &Pe[0][s][d >> 3][bb][d & 7];
        xp[k]  = x + (size_t)(b0 + bb) * (2 * NSTEP) + 2 * s;
        xv[k]  = *(const float2*)xp[k];                    // chunk-0 data
    }

    // ---- zero P (full panel rewritten each step; pads in Pe stay 0) --------
    #pragma unroll
    for (int k = 0; k < 4; ++k) ((_Float16*)P)[t + 512 * k] = (_Float16)0.0f;
    #pragma unroll
    for (int k = 0; k < 8; ++k) ((_Float16*)Pe)[t + 512 * k] = (_Float16)0.0f;
    __syncthreads();
    // fill Pe[0] with chunk 0's panel, then prefetch chunk 1's x
    #pragma unroll
    for (int k = 0; k < 3; ++k)
        if (val[k])
            pe[k][0] = (_Float16)fmaxf(fmaf(xv[k].x, we0[k], xv[k].y * we1[k]), 0.0f);
    #pragma unroll
    for (int k = 0; k < 3; ++k) { xp[k] += 2 * CHUNK; xv[k] = *(const float2*)xp[k]; }
    __syncthreads();

    // ---- ax bank 0 for chunk 0 (h(-1)=0 -> gates(0) = ax[0]) ---------------
    f32x4 xA0[CHUNK], xB0[CHUNK], xA1[CHUNK], xB1[CHUNK];
    #pragma unroll
    for (int j = 0; j < CHUNK; ++j) {
        f16x8 fe = *(const f16x8*)((const _Float16*)Pe + j * 512 + q * 128 + m * 8);
        xA0[j] = __builtin_amdgcn_mfma_f32_16x16x32_f16(whEA, fe, biasA, 0, 0, 0);
        xB0[j] = __builtin_amdgcn_mfma_f32_16x16x32_f16(whEB, fe, biasB, 0, 0, 0);
    }
    f32x4 aA = xA0[0], aB = xB0[0];

    // ---- main recurrence: NCHUNK/2 x 2 chunk-parities x CHUNK steps --------
    float cA = 0.0f, cB = 0.0f;
    for (int chp = 0; chp < NCHUNK / 2; ++chp) {
        #pragma unroll
        for (int cb = 0; cb < 2; ++cb) {
            const int ch = chp * 2 + cb;
            #pragma unroll
            for (int j = 0; j < CHUNK; ++j) {
                const int wp = j & 1;                    // panel parity for step t
                // --- act-A (lo unit) + write ---------------------------------
                float hA = lstm_act_(aA[0], aA[1], aA[2], aA[3], cA);
                hwA[wp * 1024] = (_Float16)hA;
                bar_();                                  // bar-LO: lo half ready
                // --- f0 read + mfma0 toward a(t+1); latency hides under act-B
                f16x8 f0 = *(const f16x8*)(rb + wp * 1024);
                f32x4 pA, pB;
                if (j < CHUNK - 1) {
                    pA = __builtin_amdgcn_mfma_f32_16x16x32_f16(
                        whhA[0], f0, cb == 0 ? xA0[j + 1] : xA1[j + 1], 0, 0, 0);
                    pB = __builtin_amdgcn_mfma_f32_16x16x32_f16(
                        whhB[0], f0, cb == 0 ? xB0[j + 1] : xB1[j + 1], 0, 0, 0);
                } else {
                    pA = __builtin_amdgcn_mfma_f32_16x16x32_f16(
                        whhA[0], f0, cb == 0 ? xA1[0] : xA0[0], 0, 0, 0);
                    pB = __builtin_amdgcn_mfma_f32_16x16x32_f16(
                        whhB[0], f0, cb == 0 ? xB1[0] : xB0[0], 0, 0, 0);
                }
                if (j == 0) {
                    // emb panel for chunk ch+1 into Pe[cb^1] (synced by the
                    // next 3 barriers before its j==2 readers); last chunk
                    // writes stale data to a dead buffer.
                    #pragma unroll
                    for (int k = 0; k < 3; ++k)
                        if (val[k])
                            pe[k][(cb ^ 1) * 2048] =
                                (_Float16)fmaxf(fmaf(xv[k].x, we0[k], xv[k].y * we1[k]), 0.0f);
                    if (ch + 2 < NCHUNK) {
                        #pragma unroll
                        for (int k = 0; k < 3; ++k) { xp[k] += 2 * CHUNK; xv[k] = *(const float2*)xp[k]; }
                    }
                }
                if (j == 2) {
                    // phase-B for chunk ch+1: fill the other ax bank
                    const _Float16* peN = (const _Float16*)Pe + (cb ^ 1) * 2048;
                    #pragma unroll
                    for (int j2 = 0; j2 < CHUNK; ++j2) {
                        f16x8 fe = *(const f16x8*)(peN + j2 * 512 + q * 128 + m * 8);
                        if (cb == 0) {
                            xA1[j2] = __builtin_amdgcn_mfma_f32_16x16x32_f16(whEA, fe, biasA, 0, 0, 0);
                            xB1[j2] = __builtin_amdgcn_mfma_f32_16x16x32_f16(whEB, fe, biasB, 0, 0, 0);
                        } else {
                            xA0[j2] = __builtin_amdgcn_mfma_f32_16x16x32_f16(whEA, fe, biasA, 0, 0, 0);
                            xB0[j2] = __builtin_amdgcn_mfma_f32_16x16x32_f16(whEB, fe, biasB, 0, 0, 0);
                        }
                    }
                }
                // --- act-B (hi unit) + write ---------------------------------
                float hB = lstm_act_(aB[0], aB[1], aB[2], aB[3], cB);
                hwB[wp * 1024] = (_Float16)hB;
                bar_();                                  // bar-HI: hi half ready
                // --- f1 read + mfma1 -> a(t+1) -------------------------------
                f16x8 f1 = *(const f16x8*)(rb + wp * 1024 + 512);
                aA = __builtin_amdgcn_mfma_f32_16x16x32_f16(whhA[1], f1, pA, 0, 0, 0);
                aB = __builtin_amdgcn_mfma_f32_16x16x32_f16(whhB[1], f1, pB, 0, 0, 0);
            }
        }
    }
    // final h(511) written with wp = 3&1 = 1 -> P[1]

    // ---- epilogue: h64 to fp32 (1024 values, two per thread) ---------------
    #pragma unroll
    for (int r = 0; r < 2; ++r) {
        int tt = t + 512 * r;
        int b = tt >> 6, k = tt & 63;
        h2tmp[tt] = (float)P[1][k >> 5][(k >> 3) & 3][b][k & 7];
    }
    __syncthreads();

    // ---- LSTM2 (single step, h=c=0 -> f-gate irrelevant) -------------------
    {
        const int u = t & 255;
        const int bh0 = (t >> 8) * 8;               // 2 groups x 8 batches
        float acci[8], accg[8], acco[8];
        float bi2 = b2[u], bg2 = b2[512 + u], bo2 = b2[768 + u];
        #pragma unroll
        for (int b = 0; b < 8; ++b) { acci[b] = bi2; accg[b] = bg2; acco[b] = bo2; }
        for (int k4 = 0; k4 < 64; k4 += 4) {
            float4 wi = *(const float4*)&Wih2[(size_t)u * 64 + k4];
            float4 wg = *(const float4*)&Wih2[(size_t)(512 + u) * 64 + k4];
            float4 wo = *(const float4*)&Wih2[(size_t)(768 + u) * 64 + k4];
            #pragma unroll
            for (int b = 0; b < 8; ++b) {
                float4 hb = *(const float4*)&h2tmp[(bh0 + b) * 64 + k4];
                acci[b] += wi.x * hb.x + wi.y * hb.y + wi.z * hb.z + wi.w * hb.w;
                accg[b] += wg.x * hb.x + wg.y * hb.y + wg.z * hb.z + wg.w * hb.w;
                acco[b] += wo.x * hb.x + wo.y * hb.y + wo.z * hb.z + wo.w * hb.w;
            }
        }
        #pragma unroll
        for (int b = 0; b < 8; ++b) {
            float c2 = sig_(acci[b]) * tanh_(accg[b]);
            h2s[u * 16 + bh0 + b] = sig_(acco[b]) * tanh_(c2);
        }
    }
    __syncthreads();

    // ---- output projection --------------------------------------------------
    {
        int b = t & 15, grp = t >> 4;            // 32 groups x 8 units
        float p0 = 0.f, p1 = 0.f;
        #pragma unroll
        for (int uu = grp * 8; uu < grp * 8 + 8; ++uu) {
            float hvv = h2s[uu * 16 + b];
            p0 += hvv * Wout[uu];
            p1 += hvv * Wout[256 + uu];
        }
        part[(grp * 16 + b) * 2 + 0] = p0;
        part[(grp * 16 + b) * 2 + 1] = p1;
    }
    __syncthreads();
    if (t < 32) {
        int b = t >> 1, o = t & 1;
        float s0 = bout[o];
        for (int grp = 0; grp < 32; ++grp) s0 += part[(grp * 16 + b) * 2 + o];
        out[(size_t)(b0 + b) * 2 + o] = s0;
    }
}

extern "C" void kernel_launch(void* const* d_in, const int* in_sizes, int n_in,
                              void* d_out, int out_size, void* d_ws, size_t ws_size,
                              hipStream_t stream) {
    const float* x    = (const float*)d_in[0];
    const float* Wemb = (const float*)d_in[1];
    const float* Wih1 = (const float*)d_in[2];
    const float* Whh1 = (const float*)d_in[3];
    const float* b1   = (const float*)d_in[4];
    const float* Wih2 = (const float*)d_in[5];
    // d_in[6] = Whh2: unused (h=c=0 at LSTM2's single step)
    const float* b2   = (const float*)d_in[7];
    const float* Wout = (const float*)d_in[8];
    const float* bout = (const float*)d_in[9];
    float* out = (float*)d_out;

    lstm_mfma16_kernel<<<256, 512, 0, stream>>>(
        x, Wemb, Wih1, Whh1, b1, Wih2, b2, Wout, bout, out);
}

// Round 7
// 314.872 us; speedup vs baseline: 1.3655x; 1.1245x over previous
//
#include <hip/hip_runtime.h>

typedef _Float16 f16x8 __attribute__((ext_vector_type(8)));
typedef float    f32x4 __attribute__((ext_vector_type(4)));

#define NSTEP 512
#define CHUNK 8
#define NCHUNK (NSTEP / CHUNK)
#define LOG2E     1.4426950408889634f
#define TWOLOG2E  2.8853900817779268f

__device__ __forceinline__ float exp2_(float v) { return __builtin_amdgcn_exp2f(v); }

// Exp2-domain 7-trans LSTM activation. Gates arrive PRE-SCALED from the MFMA:
// gi,gf,go = -log2(e)*(preact), gg = +2log2(e)*(preact).
__device__ __forceinline__ float lstm_act_(float gi, float gf, float gg, float go, float& c) {
    float eg = exp2_(gg);
    float ei = exp2_(gi);
    float ef = exp2_(gf);
    float eo = exp2_(go);
    float X  = (eg + 1.0f) * (1.0f + ei);
    float Y  = 1.0f + ef;
    float r  = __builtin_amdgcn_rcpf(X * Y);
    c = fmaf(r * X, c, (eg - 1.0f) * (r * Y));
    float ec = exp2_(fminf(c * TWOLOG2E, 30.0f));
    float r2 = __builtin_amdgcn_rcpf((ec + 1.0f) * (1.0f + eo));
    return (ec - 1.0f) * r2;
}
__device__ __forceinline__ float sig_(float v) {
    return __builtin_amdgcn_rcpf(1.0f + exp2_(-v * LOG2E));
}
__device__ __forceinline__ float tanh_(float v) {
    return 1.0f - 2.0f * __builtin_amdgcn_rcpf(exp2_(v * TWOLOG2E) + 1.0f);
}

// lgkmcnt-only barrier: does NOT drain vmcnt, so global x-prefetch loads float
// across the whole chunk. asm "memory" fences pin LDS ops on both sides.
__device__ __forceinline__ void bar_() {
    asm volatile("s_waitcnt lgkmcnt(0)" ::: "memory");
    __builtin_amdgcn_s_barrier();
    asm volatile("" ::: "memory");
}

// R22 = R18 base (8 waves x 2 tiles, 1 bar/step) + chain flattening:
//  (1) independent MFMA pair (a0 = whh0*f0 + ax, a1 = whh1*f1 + 0) combined
//      with 4 adds -- removes one MFMA-latency hop from the serial chain
//      (R16-verified summation order).
//  (2) per-step pipelined ax: each step reads fe(t+1) and computes ax(t+1)
//      (2 MFMAs, dependency-free filler that overlaps this step's ds_read/
//      MFMA latency). No phase-B burst, no CHUNK-deep ax register banks.
//  (3) chunk-parity (cb) unrolled -> every LDS offset is base + immediate.
__global__ __launch_bounds__(512, 2) void lstm_mfma16_kernel(
    const float* __restrict__ x,     const float* __restrict__ Wemb,
    const float* __restrict__ Wih1,  const float* __restrict__ Whh1,
    const float* __restrict__ b1,    const float* __restrict__ Wih2,
    const float* __restrict__ b2,    const float* __restrict__ Wout,
    const float* __restrict__ bout,  float* __restrict__ out)
{
    __shared__ __align__(16) _Float16 P[2][2][4][16][8];       // 4096 B  h-panel dbuf
    __shared__ __align__(16) _Float16 Pe[2][CHUNK][4][16][8];  // 16384 B emb panel dbuf
    __shared__ __align__(16) float h2tmp[16 * 64];             // 4096 B
    __shared__ __align__(16) float h2s[256 * 16];              // 16384 B
    __shared__ float part[32 * 16 * 2];                        // 4096 B

    const int t   = threadIdx.x;
    const int l   = t & 63;
    const int w   = t >> 6;      // wave 0..7; owns tiles 2w, 2w+1
    const int m   = l & 15;      // A-row / B col (batch) / D col
    const int q   = l >> 4;      // quad
    const int b0  = blockIdx.x * 16;

    // ---- weight fragments for both tiles (exp2-domain scaled) --------------
    f16x8 whh[2][2], whE[2];
    f32x4 bias4[2];
    #pragma unroll
    for (int tt = 0; tt < 2; ++tt) {
        const int tau = 2 * w + tt;
        const int g = m & 3;
        const float sc = (g == 2) ? TWOLOG2E : -LOG2E;
        const int n = g * 64 + 4 * tau + (m >> 2);
        #pragma unroll
        for (int c = 0; c < 2; ++c)
            #pragma unroll
            for (int jj = 0; jj < 8; ++jj)
                whh[tt][c][jj] = (_Float16)(Whh1[n * 64 + c * 32 + (q << 3) + jj] * sc);
        #pragma unroll
        for (int jj = 0; jj < 8; ++jj) {
            int k = (q << 3) + jj;
            whE[tt][jj] = (_Float16)((k < 20) ? Wih1[n * 20 + k] * sc : 0.0f);
        }
        #pragma unroll
        for (int r = 0; r < 4; ++r) {
            float scr = (r == 2) ? TWOLOG2E : -LOG2E;
            bias4[tt][r] = b1[r * 64 + 4 * tau + q] * scr;
        }
    }
    const f32x4 z4 = {0.f, 0.f, 0.f, 0.f};

    // lane's act cells: units 8w+q (tile A), 8w+4+q (tile B), batch m
    const int myuA = 8 * w + q;
    const int myuB = 8 * w + 4 + q;
    _Float16* hwA = &P[0][myuA >> 5][(myuA >> 3) & 3][m][myuA & 7];
    _Float16* hwB = &P[0][myuB >> 5][(myuB >> 3) & 3][m][myuB & 7];
    const _Float16* rb = &P[0][0][q][m][0];   // B-fragment base (lane-linear)
    const _Float16* base_pe = (const _Float16*)Pe + q * 128 + m * 8;
    // P parity stride = 1024 f16; Pe buffer stride = 4096 f16, step stride 512

    // ---- emb writer slots: v = t + 512k, k=0..4 (2560 = 5*512, all valid) --
    // pair = v/20 -> (batch = pair&15, s = pair>>4), dim d = v%20
    const float* xp[5]; _Float16* pe[5];
    float we0[5], we1[5];
    float2 xv[5];
    #pragma unroll
    for (int k = 0; k < 5; ++k) {
        int v  = t + 512 * k;
        int d  = v % 20, pr = v / 20;
        int bb = pr & 15, s = pr >> 4;
        we0[k] = Wemb[2 * d];
        we1[k] = Wemb[2 * d + 1];
        pe[k]  = &Pe[0][s][d >> 3][bb][d & 7];
        xp[k]  = x + (size_t)(b0 + bb) * (2 * NSTEP) + 2 * s;
        xv[k]  = *(const float2*)xp[k];                    // chunk-0 data
    }

    // ---- zero P (h(-1)=0) and all of Pe (pads d=20..31 stay 0 forever) -----
    ((_Float16*)P)[t]       = (_Float16)0.0f;
    ((_Float16*)P)[t + 512] = (_Float16)0.0f;
    ((_Float16*)P)[t + 1024] = (_Float16)0.0f;
    ((_Float16*)P)[t + 1536] = (_Float16)0.0f;
    {
        _Float16* pz = (_Float16*)Pe;
        #pragma unroll
        for (int k = 0; k < 16; ++k) pz[t + 512 * k] = (_Float16)0.0f;
    }
    __syncthreads();
    // fill Pe[0] with chunk 0's panel, then prefetch chunk 1's x
    #pragma unroll
    for (int k = 0; k < 5; ++k)
        pe[k][0] = (_Float16)fmaxf(fmaf(xv[k].x, we0[k], xv[k].y * we1[k]), 0.0f);
    #pragma unroll
    for (int k = 0; k < 5; ++k) { xp[k] += 2 * CHUNK; xv[k] = *(const float2*)xp[k]; }
    __syncthreads();

    // ---- ax for step 0 (h(-1)=0 so gates(0) = ax(0); P is zeroed) ----------
    f32x4 axA, axB;
    {
        f16x8 fe0 = *(const f16x8*)(base_pe);
        axA = __builtin_amdgcn_mfma_f32_16x16x32_f16(whE[0], fe0, bias4[0], 0, 0, 0);
        axB = __builtin_amdgcn_mfma_f32_16x16x32_f16(whE[1], fe0, bias4[1], 0, 0, 0);
    }

    // ---- main recurrence: NCHUNK/2 x 2 chunk-parities x CHUNK steps --------
    float cA = 0.0f, cB = 0.0f;
    for (int chp = 0; chp < NCHUNK / 2; ++chp) {
        #pragma unroll
        for (int cb = 0; cb < 2; ++cb) {
            const int ch = 2 * chp + cb;
            #pragma unroll
            for (int j = 0; j < CHUNK; ++j) {
                const int pr = j & 1;
                // current-step h-panel reads
                f16x8 f0 = *(const f16x8*)(rb + pr * 1024);
                f16x8 f1 = *(const f16x8*)(rb + pr * 1024 + 512);
                // next-step fe read + ax MFMAs (dependency-free filler).
                // At the last step of the last chunk this reads a stale
                // buffer; the result is discarded when the loop exits.
                const int nxt = (j < CHUNK - 1) ? (cb * 4096 + (j + 1) * 512)
                                                : ((cb ^ 1) * 4096);
                f16x8 feN = *(const f16x8*)(base_pe + nxt);
                f32x4 nA = __builtin_amdgcn_mfma_f32_16x16x32_f16(whE[0], feN, bias4[0], 0, 0, 0);
                f32x4 nB = __builtin_amdgcn_mfma_f32_16x16x32_f16(whE[1], feN, bias4[1], 0, 0, 0);
                // independent MFMA pair per tile, combined with adds
                f32x4 aA0 = __builtin_amdgcn_mfma_f32_16x16x32_f16(whh[0][0], f0, axA, 0, 0, 0);
                f32x4 aB0 = __builtin_amdgcn_mfma_f32_16x16x32_f16(whh[1][0], f0, axB, 0, 0, 0);
                f32x4 aA1 = __builtin_amdgcn_mfma_f32_16x16x32_f16(whh[0][1], f1, z4, 0, 0, 0);
                f32x4 aB1 = __builtin_amdgcn_mfma_f32_16x16x32_f16(whh[1][1], f1, z4, 0, 0, 0);
                float hA = lstm_act_(aA0[0] + aA1[0], aA0[1] + aA1[1],
                                     aA0[2] + aA1[2], aA0[3] + aA1[3], cA);
                hwA[(pr ^ 1) * 1024] = (_Float16)hA;
                float hB = lstm_act_(aB0[0] + aB1[0], aB0[1] + aB1[1],
                                     aB0[2] + aB1[2], aB0[3] + aB1[3], cB);
                hwB[(pr ^ 1) * 1024] = (_Float16)hB;
                if (j == 0) {
                    // emb panel for chunk ch+1 into Pe[cb^1]; first read of
                    // that buffer is 7 barriers later (j==7 feN). Last chunk
                    // writes stale data to a dead buffer.
                    #pragma unroll
                    for (int k = 0; k < 5; ++k)
                        pe[k][(cb ^ 1) * 4096] =
                            (_Float16)fmaxf(fmaf(xv[k].x, we0[k], xv[k].y * we1[k]), 0.0f);
                    if (ch + 2 < NCHUNK) {
                        #pragma unroll
                        for (int k = 0; k < 5; ++k) { xp[k] += 2 * CHUNK; xv[k] = *(const float2*)xp[k]; }
                    }
                }
                axA = nA; axB = nB;
                bar_();
            }
        }
    }
    // final h(511) written at j=7 -> P[0]

    // ---- epilogue: h64 to fp32 (1024 values, two per thread) ---------------
    #pragma unroll
    for (int r = 0; r < 2; ++r) {
        int tt = t + 512 * r;
        int b = tt >> 6, k = tt & 63;
        h2tmp[tt] = (float)P[0][k >> 5][(k >> 3) & 3][b][k & 7];
    }
    __syncthreads();

    // ---- LSTM2 (single step, h=c=0 -> f-gate irrelevant) -------------------
    {
        const int u = t & 255;
        const int bh0 = (t >> 8) * 8;               // 2 groups x 8 batches
        float acci[8], accg[8], acco[8];
        float bi2 = b2[u], bg2 = b2[512 + u], bo2 = b2[768 + u];
        #pragma unroll
        for (int b = 0; b < 8; ++b) { acci[b] = bi2; accg[b] = bg2; acco[b] = bo2; }
        for (int k4 = 0; k4 < 64; k4 += 4) {
            float4 wi = *(const float4*)&Wih2[(size_t)u * 64 + k4];
            float4 wg = *(const float4*)&Wih2[(size_t)(512 + u) * 64 + k4];
            float4 wo = *(const float4*)&Wih2[(size_t)(768 + u) * 64 + k4];
            #pragma unroll
            for (int b = 0; b < 8; ++b) {
                float4 hb = *(const float4*)&h2tmp[(bh0 + b) * 64 + k4];
                acci[b] += wi.x * hb.x + wi.y * hb.y + wi.z * hb.z + wi.w * hb.w;
                accg[b] += wg.x * hb.x + wg.y * hb.y + wg.z * hb.z + wg.w * hb.w;
                acco[b] += wo.x * hb.x + wo.y * hb.y + wo.z * hb.z + wo.w * hb.w;
            }
        }
        #pragma unroll
        for (int b = 0; b < 8; ++b) {
            float c2 = sig_(acci[b]) * tanh_(accg[b]);
            h2s[u * 16 + bh0 + b] = sig_(acco[b]) * tanh_(c2);
        }
    }
    __syncthreads();

    // ---- output projection --------------------------------------------------
    {
        int b = t & 15, grp = t >> 4;            // 32 groups x 8 units
        float p0 = 0.f, p1 = 0.f;
        #pragma unroll
        for (int uu = grp * 8; uu < grp * 8 + 8; ++uu) {
            float hvv = h2s[uu * 16 + b];
            p0 += hvv * Wout[uu];
            p1 += hvv * Wout[256 + uu];
        }
        part[(grp * 16 + b) * 2 + 0] = p0;
        part[(grp * 16 + b) * 2 + 1] = p1;
    }
    __syncthreads();
    if (t < 32) {
        int b = t >> 1, o = t & 1;
        float s0 = bout[o];
        for (int grp = 0; grp < 32; ++grp) s0 += part[(grp * 16 + b) * 2 + o];
        out[(size_t)(b0 + b) * 2 + o] = s0;
    }
}

extern "C" void kernel_launch(void* const* d_in, const int* in_sizes, int n_in,
                              void* d_out, int out_size, void* d_ws, size_t ws_size,
                              hipStream_t stream) {
    const float* x    = (const float*)d_in[0];
    const float* Wemb = (const float*)d_in[1];
    const float* Wih1 = (const float*)d_in[2];
    const float* Whh1 = (const float*)d_in[3];
    const float* b1   = (const float*)d_in[4];
    const float* Wih2 = (const float*)d_in[5];
    // d_in[6] = Whh2: unused (h=c=0 at LSTM2's single step)
    const float* b2   = (const float*)d_in[7];
    const float* Wout = (const float*)d_in[8];
    const float* bout = (const float*)d_in[9];
    float* out = (float*)d_out;

    lstm_mfma16_kernel<<<256, 512, 0, stream>>>(
        x, Wemb, Wih1, Whh1, b1, Wih2, b2, Wout, bout, out);
}

// Round 8
// 280.536 us; speedup vs baseline: 1.5326x; 1.1224x over previous
//
#include <hip/hip_runtime.h>

typedef _Float16 f16x8 __attribute__((ext_vector_type(8)));
typedef float    f32x4 __attribute__((ext_vector_type(4)));
typedef float    f32x2 __attribute__((ext_vector_type(2)));

#define NSTEP 512
#define CHUNK 8
#define NCHUNK (NSTEP / CHUNK)
#define LOG2E     1.4426950408889634f
#define TWOLOG2E  2.8853900817779268f

__device__ __forceinline__ float exp2_(float v) { return __builtin_amdgcn_exp2f(v); }

// Packed-pair exp2-domain LSTM activation: the A/B cells' independent
// element-wise chains computed as float2 so the backend can emit
// v_pk_fma/add/mul_f32 for the arithmetic (trans ops remain scalar).
// Gates arrive PRE-SCALED from the MFMA: gi,gf,go = -log2e*preact,
// gg = +2log2e*preact. Same fused ops / same order as the scalar version.
__device__ __forceinline__ f32x2 exp2v_(f32x2 v) {
    f32x2 r; r[0] = exp2_(v[0]); r[1] = exp2_(v[1]); return r;
}
__device__ __forceinline__ f32x2 rcpv_(f32x2 v) {
    f32x2 r; r[0] = __builtin_amdgcn_rcpf(v[0]); r[1] = __builtin_amdgcn_rcpf(v[1]); return r;
}
__device__ __forceinline__ f32x2 lstm_act2_(f32x2 gi, f32x2 gf, f32x2 gg, f32x2 go, f32x2& c) {
    const f32x2 one = {1.0f, 1.0f};
    f32x2 eg = exp2v_(gg);
    f32x2 ei = exp2v_(gi);
    f32x2 ef = exp2v_(gf);
    f32x2 eo = exp2v_(go);
    f32x2 X  = (eg + one) * (one + ei);
    f32x2 Y  = one + ef;
    f32x2 r  = rcpv_(X * Y);
    c = (r * X) * c + (eg - one) * (r * Y);
    f32x2 ec;
    ec[0] = exp2_(fminf(c[0] * TWOLOG2E, 30.0f));
    ec[1] = exp2_(fminf(c[1] * TWOLOG2E, 30.0f));
    f32x2 r2 = rcpv_((ec + one) * (one + eo));
    return (ec - one) * r2;
}
__device__ __forceinline__ float sig_(float v) {
    return __builtin_amdgcn_rcpf(1.0f + exp2_(-v * LOG2E));
}
__device__ __forceinline__ float tanh_(float v) {
    return 1.0f - 2.0f * __builtin_amdgcn_rcpf(exp2_(v * TWOLOG2E) + 1.0f);
}

// lgkmcnt-only barrier: does NOT drain vmcnt, so global x-prefetch loads float
// across the whole chunk. asm "memory" fences pin LDS ops on both sides.
__device__ __forceinline__ void bar_() {
    asm volatile("s_waitcnt lgkmcnt(0)" ::: "memory");
    __builtin_amdgcn_s_barrier();
    asm volatile("" ::: "memory");
}

// R23 = R18 (structural optimum: 8 waves x 2 tiles, 1 bar/step, chunk-burst
// ax, chained MFMA pair, vmcnt-floating prefetch) + issue-stream cuts:
//  (1) packed-pair A/B activation (v_pk_* for ~10 arith ops/act),
//  (2) emb-panel writes spread one-per-step over j=1..5 (prefetch at j=6)
//      instead of a 5-write lump at j==0.
__global__ __launch_bounds__(512, 2) void lstm_mfma16_kernel(
    const float* __restrict__ x,     const float* __restrict__ Wemb,
    const float* __restrict__ Wih1,  const float* __restrict__ Whh1,
    const float* __restrict__ b1,    const float* __restrict__ Wih2,
    const float* __restrict__ b2,    const float* __restrict__ Wout,
    const float* __restrict__ bout,  float* __restrict__ out)
{
    __shared__ __align__(16) _Float16 P[2][2][4][16][8];       // 4096 B  h-panel dbuf
    __shared__ __align__(16) _Float16 Pe[2][CHUNK][4][16][8];  // 16384 B emb panel dbuf
    __shared__ __align__(16) float h2tmp[16 * 64];             // 4096 B
    __shared__ __align__(16) float h2s[256 * 16];              // 16384 B
    __shared__ float part[32 * 16 * 2];                        // 4096 B

    const int t   = threadIdx.x;
    const int l   = t & 63;
    const int w   = t >> 6;      // wave 0..7; owns tiles 2w, 2w+1
    const int m   = l & 15;      // A-row / B col (batch) / D col
    const int q   = l >> 4;      // quad
    const int b0  = blockIdx.x * 16;

    // ---- weight fragments for both tiles (exp2-domain scaled) --------------
    f16x8 whh[2][2], whE[2];
    f32x4 bias4[2];
    #pragma unroll
    for (int tt = 0; tt < 2; ++tt) {
        const int tau = 2 * w + tt;
        const int g = m & 3;
        const float sc = (g == 2) ? TWOLOG2E : -LOG2E;
        const int n = g * 64 + 4 * tau + (m >> 2);
        #pragma unroll
        for (int c = 0; c < 2; ++c)
            #pragma unroll
            for (int jj = 0; jj < 8; ++jj)
                whh[tt][c][jj] = (_Float16)(Whh1[n * 64 + c * 32 + (q << 3) + jj] * sc);
        #pragma unroll
        for (int jj = 0; jj < 8; ++jj) {
            int k = (q << 3) + jj;
            whE[tt][jj] = (_Float16)((k < 20) ? Wih1[n * 20 + k] * sc : 0.0f);
        }
        #pragma unroll
        for (int r = 0; r < 4; ++r) {
            float scr = (r == 2) ? TWOLOG2E : -LOG2E;
            bias4[tt][r] = b1[r * 64 + 4 * tau + q] * scr;
        }
    }

    // lane's act cells: units 8w+q (tile A), 8w+4+q (tile B), batch m
    const int myuA = 8 * w + q;
    const int myuB = 8 * w + 4 + q;
    _Float16* hwA = &P[0][myuA >> 5][(myuA >> 3) & 3][m][myuA & 7];
    _Float16* hwB = &P[0][myuB >> 5][(myuB >> 3) & 3][m][myuB & 7];
    const _Float16* rb = &P[0][0][q][m][0];   // B-fragment base (lane-linear)
    // parity stride = one P buffer = 1024 f16; Pe buffer stride = 4096 f16

    // ---- emb writer slots: v = t + 512k, k=0..4 (2560 = 5*512, all valid) --
    // pair = v/20 -> (batch = pair&15, s = pair>>4), dim d = v%20
    const float* xp[5]; _Float16* pe[5];
    float we0[5], we1[5];
    float2 xv[5];
    #pragma unroll
    for (int k = 0; k < 5; ++k) {
        int v  = t + 512 * k;
        int d  = v % 20, pr = v / 20;
        int bb = pr & 15, s = pr >> 4;
        we0[k] = Wemb[2 * d];
        we1[k] = Wemb[2 * d + 1];
        pe[k]  = &Pe[0][s][d >> 3][bb][d & 7];
        xp[k]  = x + (size_t)(b0 + bb) * (2 * NSTEP) + 2 * s;
        xv[k]  = *(const float2*)xp[k];                    // chunk-0 data
    }

    // ---- zero P[0] (h(-1)=0) and all of Pe (pads d=20..31 stay 0 forever) --
    ((_Float16*)P)[t]       = (_Float16)0.0f;
    ((_Float16*)P)[t + 512] = (_Float16)0.0f;
    {
        _Float16* pz = (_Float16*)Pe;
        #pragma unroll
        for (int k = 0; k < 16; ++k) pz[t + 512 * k] = (_Float16)0.0f;
    }
    __syncthreads();
    // fill Pe[0] with chunk 0's panel, then prefetch chunk 1's x
    #pragma unroll
    for (int k = 0; k < 5; ++k)
        pe[k][0] = (_Float16)fmaxf(fmaf(xv[k].x, we0[k], xv[k].y * we1[k]), 0.0f);
    #pragma unroll
    for (int k = 0; k < 5; ++k) { xp[k] += 2 * CHUNK; xv[k] = *(const float2*)xp[k]; }
    __syncthreads();

    // ---- main recurrence: 64 chunks x 8 steps ------------------------------
    f32x2 cst = {0.0f, 0.0f};
    for (int ch = 0; ch < NCHUNK; ++ch) {
        const int pb = ch & 1;                           // Pe read buffer
        const _Float16* peR = (const _Float16*)Pe + pb * 4096;

        // phase B: ax[tile][j] = Wih*e(t) + b, in registers (lane == consumer)
        f32x4 axA[CHUNK], axB[CHUNK];
        #pragma unroll
        for (int j = 0; j < CHUNK; ++j) {
            f16x8 fe = *(const f16x8*)(peR + j * 512 + q * 128 + m * 8);
            axA[j] = __builtin_amdgcn_mfma_f32_16x16x32_f16(whE[0], fe, bias4[0], 0, 0, 0);
            axB[j] = __builtin_amdgcn_mfma_f32_16x16x32_f16(whE[1], fe, bias4[1], 0, 0, 0);
        }

        // phase C: 8 recurrence steps, parity static per unrolled slot
        #pragma unroll
        for (int j = 0; j < CHUNK; ++j) {
            const int pr = j & 1;
            f16x8 f0 = *(const f16x8*)(rb + pr * 1024);
            f16x8 f1 = *(const f16x8*)(rb + pr * 1024 + 512);
            f32x4 aA = __builtin_amdgcn_mfma_f32_16x16x32_f16(whh[0][0], f0, axA[j], 0, 0, 0);
            f32x4 aB = __builtin_amdgcn_mfma_f32_16x16x32_f16(whh[1][0], f0, axB[j], 0, 0, 0);
            aA = __builtin_amdgcn_mfma_f32_16x16x32_f16(whh[0][1], f1, aA, 0, 0, 0);
            aB = __builtin_amdgcn_mfma_f32_16x16x32_f16(whh[1][1], f1, aB, 0, 0, 0);
            f32x2 gi = {aA[0], aB[0]}, gf = {aA[1], aB[1]};
            f32x2 gg = {aA[2], aB[2]}, go = {aA[3], aB[3]};
            f32x2 hv = lstm_act2_(gi, gf, gg, go, cst);
            hwA[(pr ^ 1) * 1024] = (_Float16)hv[0];
            hwB[(pr ^ 1) * 1024] = (_Float16)hv[1];
            // emb writes for chunk ch+1 spread one per step (j=1..5);
            // x prefetch for chunk ch+2 at j=6. Pe[pb^1]'s first reader is
            // next chunk's phase B (after this chunk's last barrier);
            // last chunk writes stale data to a dead buffer.
            if (j >= 1 && j <= 5) {
                const int k = j - 1;
                pe[k][(pb ^ 1) * 4096] =
                    (_Float16)fmaxf(fmaf(xv[k].x, we0[k], xv[k].y * we1[k]), 0.0f);
            }
            if (j == 6 && ch + 2 < NCHUNK) {
                #pragma unroll
                for (int k = 0; k < 5; ++k) { xp[k] += 2 * CHUNK; xv[k] = *(const float2*)xp[k]; }
            }
            bar_();
        }
    }
    // final h(511) in P[0]

    // ---- epilogue: h64 to fp32 (1024 values, two per thread) ---------------
    #pragma unroll
    for (int r = 0; r < 2; ++r) {
        int tt = t + 512 * r;
        int b = tt >> 6, k = tt & 63;
        h2tmp[tt] = (float)P[0][k >> 5][(k >> 3) & 3][b][k & 7];
    }
    __syncthreads();

    // ---- LSTM2 (single step, h=c=0 -> f-gate irrelevant) -------------------
    {
        const int u = t & 255;
        const int bh0 = (t >> 8) * 8;               // 2 groups x 8 batches
        float acci[8], accg[8], acco[8];
        float bi2 = b2[u], bg2 = b2[512 + u], bo2 = b2[768 + u];
        #pragma unroll
        for (int b = 0; b < 8; ++b) { acci[b] = bi2; accg[b] = bg2; acco[b] = bo2; }
        for (int k4 = 0; k4 < 64; k4 += 4) {
            float4 wi = *(const float4*)&Wih2[(size_t)u * 64 + k4];
            float4 wg = *(const float4*)&Wih2[(size_t)(512 + u) * 64 + k4];
            float4 wo = *(const float4*)&Wih2[(size_t)(768 + u) * 64 + k4];
            #pragma unroll
            for (int b = 0; b < 8; ++b) {
                float4 hb = *(const float4*)&h2tmp[(bh0 + b) * 64 + k4];
                acci[b] += wi.x * hb.x + wi.y * hb.y + wi.z * hb.z + wi.w * hb.w;
                accg[b] += wg.x * hb.x + wg.y * hb.y + wg.z * hb.z + wg.w * hb.w;
                acco[b] += wo.x * hb.x + wo.y * hb.y + wo.z * hb.z + wo.w * hb.w;
            }
        }
        #pragma unroll
        for (int b = 0; b < 8; ++b) {
            float c2 = sig_(acci[b]) * tanh_(accg[b]);
            h2s[u * 16 + bh0 + b] = sig_(acco[b]) * tanh_(c2);
        }
    }
    __syncthreads();

    // ---- output projection --------------------------------------------------
    {
        int b = t & 15, grp = t >> 4;            // 32 groups x 8 units
        float p0 = 0.f, p1 = 0.f;
        #pragma unroll
        for (int uu = grp * 8; uu < grp * 8 + 8; ++uu) {
            float hvv = h2s[uu * 16 + b];
            p0 += hvv * Wout[uu];
            p1 += hvv * Wout[256 + uu];
        }
        part[(grp * 16 + b) * 2 + 0] = p0;
        part[(grp * 16 + b) * 2 + 1] = p1;
    }
    __syncthreads();
    if (t < 32) {
        int b = t >> 1, o = t & 1;
        float s0 = bout[o];
        for (int grp = 0; grp < 32; ++grp) s0 += part[(grp * 16 + b) * 2 + o];
        out[(size_t)(b0 + b) * 2 + o] = s0;
    }
}

extern "C" void kernel_launch(void* const* d_in, const int* in_sizes, int n_in,
                              void* d_out, int out_size, void* d_ws, size_t ws_size,
                              hipStream_t stream) {
    const float* x    = (const float*)d_in[0];
    const float* Wemb = (const float*)d_in[1];
    const float* Wih1 = (const float*)d_in[2];
    const float* Whh1 = (const float*)d_in[3];
    const float* b1   = (const float*)d_in[4];
    const float* Wih2 = (const float*)d_in[5];
    // d_in[6] = Whh2: unused (h=c=0 at LSTM2's single step)
    const float* b2   = (const float*)d_in[7];
    const float* Wout = (const float*)d_in[8];
    const float* bout = (const float*)d_in[9];
    float* out = (float*)d_out;

    lstm_mfma16_kernel<<<256, 512, 0, stream>>>(
        x, Wemb, Wih1, Whh1, b1, Wih2, b2, Wout, bout, out);
}